// Round 8
// baseline (117.045 us; speedup 1.0000x reference)
//
#include <hip/hip_runtime.h>

typedef unsigned short ushort_t;
typedef __attribute__((ext_vector_type(8))) short bf16x8;
typedef __attribute__((ext_vector_type(8))) unsigned short ushort8;
typedef __attribute__((ext_vector_type(4))) float f32x4;

__device__ __forceinline__ unsigned short f2bf(float f) {
  union { float f; unsigned u; } x; x.f = f;
  unsigned r = x.u + 0x7FFFu + ((x.u >> 16) & 1u);   // round-to-nearest-even
  return (unsigned short)(r >> 16);
}

// ---------------- chain part 1: g[b][q][y][c][z] = sum_r f1[b,q,r,y]*lf[c,r,z]
__global__ void chain_g_kernel(const float* __restrict__ f1,
                               const float* __restrict__ lf,
                               float* __restrict__ g) {
  int idx = blockIdx.x * 256 + threadIdx.x;           // 32768 total
  int z = idx & 7, c = (idx >> 3) & 3, y = (idx >> 5) & 7,
      q = (idx >> 8) & 15, b = idx >> 12;
  float s = 0.f;
  #pragma unroll
  for (int r = 0; r < 16; ++r)
    s += f1[((b * 16 + q) * 16 + r) * 8 + y] * lf[(c * 16 + r) * 8 + z];
  g[idx] = s;
}

// ---------------- chain part 2: chainT[o][k] = sum_q f0[a,p,q,x]*g[b,q,y,c,z]
// o = (x*8+y)*8+z ; k = ((a*8+b)*4+c)*4+p
__global__ void chain_kernel(const float* __restrict__ f0,
                             const float* __restrict__ g,
                             ushort_t* __restrict__ chainT) {
  int idx = blockIdx.x * 256 + threadIdx.x;           // 524288 total = o*1024+k
  int k = idx & 1023, o = idx >> 10;
  int p = k & 3, c = (k >> 2) & 3, b = (k >> 4) & 7, a = k >> 7;
  int z = o & 7, y = (o >> 3) & 7, x = o >> 6;
  float s = 0.f;
  #pragma unroll
  for (int q = 0; q < 16; ++q)
    s += f0[((a * 4 + p) * 16 + q) * 8 + x] *
         g[(((b * 16 + q) * 8 + y) * 4 + c) * 8 + z];
  chainT[idx] = f2bf(s);
}

// ---------------- depthwise 3x3 conv -> t[m][k] bf16 (K-contiguous)
// block = (n, h-quad, channel-quarter). grid = 32*8*4 = 1024 blocks.
__global__ __launch_bounds__(256) void conv_kernel(const float* __restrict__ in,
                                                   const float* __restrict__ sf,
                                                   ushort_t* __restrict__ t) {
  __shared__ float in_lds[64][244];
  __shared__ float sf_l[36];
  int bid = blockIdx.x;
  int cq = bid & 3, h4 = (bid >> 2) & 7, n = bid >> 5;
  int h0 = h4 * 4;
  int tid = threadIdx.x;
  if (tid < 36) sf_l[tid] = sf[tid];
  for (int e = tid; e < 384; e += 256) {
    int ch = e / 6, r = e % 6;
    in_lds[ch][r * 40 + 3] = 0.f;
    in_lds[ch][r * 40 + 36] = 0.f;
  }
  const float* inb = in + ((size_t)n * 256 + cq * 64) * 1024;
  #pragma unroll
  for (int i = 0; i < 12; ++i) {
    int e = tid + i * 256;
    int ch = e / 48, rem = e % 48;
    int r = rem >> 3, w4 = rem & 7;
    int hh = h0 - 1 + r;
    float4 v = make_float4(0.f, 0.f, 0.f, 0.f);
    if (hh >= 0 && hh < 32)
      v = *(const float4*)&inb[(size_t)ch * 1024 + hh * 32 + w4 * 4];
    *(float4*)&in_lds[ch][r * 40 + 4 + w4 * 4] = v;
  }
  __syncthreads();
  float sfr[36];
  #pragma unroll
  for (int i = 0; i < 36; ++i) sfr[i] = sf_l[i];
  int w = tid >> 3, gg = tid & 7;
  size_t m0 = (size_t)n * 1024 + (size_t)h0 * 32 + w;
  #pragma unroll
  for (int j = 0; j < 4; ++j) {
    float acc[4][2][4];
    #pragma unroll
    for (int b = 0; b < 2; ++b) {
      int ch = j * 16 + gg * 2 + b;
      float vals[6][3];
      #pragma unroll
      for (int r = 0; r < 6; ++r)
        #pragma unroll
        for (int dw = 0; dw < 3; ++dw)
          vals[r][dw] = in_lds[ch][r * 40 + 3 + w + dw];
      #pragma unroll
      for (int hh = 0; hh < 4; ++hh)
        #pragma unroll
        for (int p = 0; p < 4; ++p) {
          float s = 0.f;
          #pragma unroll
          for (int dr = 0; dr < 3; ++dr)
            #pragma unroll
            for (int dw = 0; dw < 3; ++dw)
              s += vals[hh + dr][dw] * sfr[p * 9 + dr * 3 + dw];
          acc[hh][b][p] = s;
        }
    }
    #pragma unroll
    for (int hh = 0; hh < 4; ++hh) {
      ushort8 outv;
      #pragma unroll
      for (int b = 0; b < 2; ++b)
        #pragma unroll
        for (int p = 0; p < 4; ++p) outv[b * 4 + p] = f2bf(acc[hh][b][p]);
      *(ushort8*)&t[(m0 + hh * 32) * 1024 + (size_t)(cq * 256 + j * 64 + gg * 8)] = outv;
    }
  }
}

// ---------------- GEMM: out[m][o] = sum_k t[m][k]*chainT[o][k] + bias[o]
// BM=128, BN=256, BK=64. 8 waves (2Mx4N -> 64x64 per wave).
// A (t) staged in LDS (32 KB dbuf, XOR swizzle, global_load_lds);
// B (chainT, 1 MB, L2-resident) read directly from global into registers.
// 2-phase sync: one {LGKMCNT0; VMCNT0; BARRIER} per K-step (per-wave vmcnt
// certified BEFORE the barrier that releases readers). Grid 512 -> 2 blocks/CU.
#define AS1 __attribute__((address_space(1)))
#define AS3 __attribute__((address_space(3)))
#define BARRIER  __builtin_amdgcn_s_barrier()
#define LGKMCNT0 asm volatile("s_waitcnt lgkmcnt(0)" ::: "memory")
#define VMCNT0   asm volatile("s_waitcnt vmcnt(0)" ::: "memory")

__global__ __launch_bounds__(512, 4) void gemm_kernel(const ushort_t* __restrict__ tA,
                                                      const ushort_t* __restrict__ tB,
                                                      const float* __restrict__ bias,
                                                      float* __restrict__ out) {
  __shared__ __align__(16) ushort_t smem[2][8192];  // A only: [buf][128 rows x 64 k]
  int tid = threadIdx.x;
  int bid = blockIdx.x;                             // 512 blocks
  int wg = (bid & 7) * 64 + (bid >> 3);             // XCD chunk swizzle (512%8==0)
  int tile_m = (wg >> 1) * 128;
  int tile_n = (wg & 1) * 256;

  int lane = tid & 63, wv = tid >> 6;
  int wm = (wv >> 2) * 64, wn = (wv & 3) * 64;      // per-wave 64x64
  int lr = lane & 15, kg = lane >> 4;
  int kph0 = ((kg * 8) ^ ((lane & 7) * 8));
  int kph1 = ((32 + kg * 8) ^ ((lane & 7) * 8));

  // A staging: thread tid covers LDS elems [buf][h*4096 + tid*8]; source pre-swizzled
  int srow = tid >> 3;                              // 0..63
  int scol = ((tid & 7) ^ (srow & 7)) * 8;
  const ushort_t* sA = tA + (size_t)(tile_m + srow) * 1024 + scol;

#define STAGE_A(buf, koff)                                                                     \
  __builtin_amdgcn_global_load_lds((const AS1 void*)(sA + (koff)),                             \
      (AS3 void*)&smem[buf][tid * 8], 16, 0, 0);                                               \
  __builtin_amdgcn_global_load_lds((const AS1 void*)(sA + (size_t)64 * 1024 + (koff)),         \
      (AS3 void*)&smem[buf][4096 + tid * 8], 16, 0, 0);

  // B row bases (per nf): chainT row (o) = tile_n + wn + nf*16 + lr
  const ushort_t* pB[4];
  #pragma unroll
  for (int nf = 0; nf < 4; ++nf)
    pB[nf] = tB + (size_t)(tile_n + wn + nf * 16 + lr) * 1024 + kg * 8;

  f32x4 acc[4][4];
  #pragma unroll
  for (int i = 0; i < 4; ++i)
    #pragma unroll
    for (int j = 0; j < 4; ++j) acc[i][j] = (f32x4){0.f, 0.f, 0.f, 0.f};

  float bv[4];
  #pragma unroll
  for (int nf = 0; nf < 4; ++nf) bv[nf] = bias[tile_n + wn + nf * 16 + lr];

  STAGE_A(0, 0)
  VMCNT0; BARRIER;

  for (int kt = 0; kt < 16; ++kt) {
    int cur = kt & 1;
    if (kt < 15) { STAGE_A(cur ^ 1, (kt + 1) * 64) }
    #pragma unroll
    for (int ks = 0; ks < 2; ++ks) {
      int kph = ks ? kph1 : kph0;
      bf16x8 af[4], bfv[4];
      #pragma unroll
      for (int mf = 0; mf < 4; ++mf)
        af[mf] = *(const bf16x8*)&smem[cur][(wm + mf * 16 + lr) * 64 + kph];
      #pragma unroll
      for (int nf = 0; nf < 4; ++nf)
        bfv[nf] = *(const bf16x8*)&pB[nf][kt * 64 + ks * 32];
      __builtin_amdgcn_s_setprio(1);
      #pragma unroll
      for (int mf = 0; mf < 4; ++mf)
        #pragma unroll
        for (int nf = 0; nf < 4; ++nf)
          acc[mf][nf] = __builtin_amdgcn_mfma_f32_16x16x32_bf16(af[mf], bfv[nf], acc[mf][nf], 0, 0, 0);
      __builtin_amdgcn_s_setprio(0);
    }
    // ds_reads all drained (LGKMCNT0) and own A-DMA certified (VMCNT0) BEFORE
    // the barrier releases any wave into the next K-step.
    LGKMCNT0; VMCNT0; BARRIER;
  }

  // epilogue: lane holds D[m=kg*4+r][o=lr] per 16x16 frag
  #pragma unroll
  for (int mf = 0; mf < 4; ++mf)
    #pragma unroll
    for (int nf = 0; nf < 4; ++nf) {
      int m = tile_m + wm + mf * 16 + kg * 4;
      int o = tile_n + wn + nf * 16 + lr;
      f32x4 v = acc[mf][nf];
      v[0] += bv[nf]; v[1] += bv[nf]; v[2] += bv[nf]; v[3] += bv[nf];
      *(f32x4*)&out[(size_t)(m >> 10) * 524288 + (size_t)o * 1024 + (size_t)(m & 1023)] = v;
    }
}

extern "C" void kernel_launch(void* const* d_in, const int* in_sizes, int n_in,
                              void* d_out, int out_size, void* d_ws, size_t ws_size,
                              hipStream_t stream) {
  (void)in_sizes; (void)n_in; (void)out_size; (void)ws_size;
  const float* in   = (const float*)d_in[0];
  const float* sf   = (const float*)d_in[1];
  const float* f0   = (const float*)d_in[2];
  const float* f1   = (const float*)d_in[3];
  const float* lf   = (const float*)d_in[4];
  const float* bias = (const float*)d_in[5];
  float* out = (float*)d_out;

  char* ws = (char*)d_ws;
  ushort_t* t      = (ushort_t*)ws;                          // 64 MB
  ushort_t* chainT = (ushort_t*)(ws + 67108864);             // 1 MB
  float*    g      = (float*)(ws + 67108864 + 1048576);      // 128 KB

  hipLaunchKernelGGL(chain_g_kernel, dim3(128),  dim3(256), 0, stream, f1, lf, g);
  hipLaunchKernelGGL(chain_kernel,   dim3(2048), dim3(256), 0, stream, f0, g, chainT);
  hipLaunchKernelGGL(conv_kernel,    dim3(1024), dim3(256), 0, stream, in, sf, t);
  hipLaunchKernelGGL(gemm_kernel,    dim3(512),  dim3(512), 0, stream, t, chainT, bias, out);
}

// Round 9
// 76.703 us; speedup vs baseline: 1.5260x; 1.5260x over previous
//
#include <hip/hip_runtime.h>

typedef unsigned short ushort_t;
typedef __attribute__((ext_vector_type(8))) short bf16x8;
typedef __attribute__((ext_vector_type(4))) float f32x4;

__device__ __forceinline__ unsigned short f2bf(float f) {
  union { float f; unsigned u; } x; x.f = f;
  unsigned r = x.u + 0x7FFFu + ((x.u >> 16) & 1u);   // round-to-nearest-even
  return (unsigned short)(r >> 16);
}

// ---------------- chain part 1: g[b][q][y][c][z] = sum_r f1[b,q,r,y]*lf[c,r,z]
__global__ void chain_g_kernel(const float* __restrict__ f1,
                               const float* __restrict__ lf,
                               float* __restrict__ g) {
  int idx = blockIdx.x * 256 + threadIdx.x;           // 32768 total
  int z = idx & 7, c = (idx >> 3) & 3, y = (idx >> 5) & 7,
      q = (idx >> 8) & 15, b = idx >> 12;
  float s = 0.f;
  #pragma unroll
  for (int r = 0; r < 16; ++r)
    s += f1[((b * 16 + q) * 16 + r) * 8 + y] * lf[(c * 16 + r) * 8 + z];
  g[idx] = s;
}

// ---------------- chain part 2: chainT[o][k] = sum_q f0[a,p,q,x]*g[b,q,y,c,z]
// o = (x*8+y)*8+z ; k = ((a*8+b)*4+c)*4+p
__global__ void chain_kernel(const float* __restrict__ f0,
                             const float* __restrict__ g,
                             ushort_t* __restrict__ chainT) {
  int idx = blockIdx.x * 256 + threadIdx.x;           // 524288 total = o*1024+k
  int k = idx & 1023, o = idx >> 10;
  int p = k & 3, c = (k >> 2) & 3, b = (k >> 4) & 7, a = k >> 7;
  int z = o & 7, y = (o >> 3) & 7, x = o >> 6;
  float s = 0.f;
  #pragma unroll
  for (int q = 0; q < 16; ++q)
    s += f0[((a * 4 + p) * 16 + q) * 8 + x] *
         g[(((b * 16 + q) * 8 + y) * 4 + c) * 8 + z];
  chainT[idx] = f2bf(s);
}

// ---------------- FUSED: depthwise conv (in-register) + GEMM
// out[m][o] = sum_k conv(in)[m][k] * chainT[o][k] + bias[o]
// block = 128 pixels (n, 4 h-rows, 32 w), BN=512 (all o), BK=64 (16 cin x 4 p).
// Grid 256 = 1 block/CU. 8 waves (2M x 4N -> 64x128 per wave).
// A produced in-kernel: input float4 -> Is LDS (dbuf) -> shfl taps -> FMA -> bf16 -> swizzled ds_write.
// B staged per kt via global_load_lds (single buffer, L2-resident source).
// Sync: conservative full-drain 2-phase (all RAW certified producer-side pre-barrier).
#define AS1 __attribute__((address_space(1)))
#define AS3 __attribute__((address_space(3)))
#define BARRIER  __builtin_amdgcn_s_barrier()
#define LGKMCNT0 asm volatile("s_waitcnt lgkmcnt(0)" ::: "memory")
#define VMCNT0   asm volatile("s_waitcnt vmcnt(0)" ::: "memory")

__global__ __launch_bounds__(512, 2) void fused_kernel(const float* __restrict__ in,
                                                       const float* __restrict__ sf,
                                                       const ushort_t* __restrict__ chainT,
                                                       const float* __restrict__ bias,
                                                       float* __restrict__ out) {
  __shared__ __align__(16) ushort_t Bs[512 * 64];   // 64 KB, swizzled chunks
  __shared__ __align__(16) ushort_t As[128 * 64];   // 16 KB, swizzled chunks
  __shared__ __align__(16) float Is[2][16][6][32];  // 24 KB input dbuf (rows h0-1..h0+4)

  int tid = threadIdx.x;
  int bid = blockIdx.x;                             // 256 blocks
  int wg = (bid & 7) * 32 + (bid >> 3);             // XCD swizzle (256%8==0)
  int n = wg >> 3, hq = wg & 7;
  int h0 = hq * 4;

  int lane = tid & 63, wv = tid >> 6;
  int wm = (wv >> 2) * 64, wn = (wv & 3) * 128;     // per-wave 64 x 128
  int lr = lane & 15, kg = lane >> 4;
  int kph0 = ((kg * 8) ^ ((lane & 7) * 8));
  int kph1 = ((32 + kg * 8) ^ ((lane & 7) * 8));

  // B staging: thread covers chunk (tid&7) of rows srow+l*64; logical chunk pre-swizzled in source
  int srow = tid >> 3;
  int scol = ((tid & 7) ^ (srow & 7)) * 8;
  const ushort_t* sB = chainT + (size_t)srow * 1024 + scol;
  int bdst = srow * 64 + (tid & 7) * 8;

  // conv thread mapping: (w, h-pair, 2-channel group)
  int cw = tid & 31, hp = (tid >> 5) & 1, ch2 = tid >> 6;   // ch2 0..7

  // filters -> uniform (readfirstlane => SGPR candidates)
  float sfr[36];
  #pragma unroll
  for (int i = 0; i < 36; ++i)
    sfr[i] = __int_as_float(__builtin_amdgcn_readfirstlane(__float_as_int(sf[i])));

  float bv[8];
  #pragma unroll
  for (int nf = 0; nf < 8; ++nf) bv[nf] = bias[wn + nf * 16 + lr];

  f32x4 acc[4][8];
  #pragma unroll
  for (int i = 0; i < 4; ++i)
    #pragma unroll
    for (int j = 0; j < 8; ++j) acc[i][j] = (f32x4){0.f, 0.f, 0.f, 0.f};

  const float* inb = in + (size_t)n * 256 * 1024;

#define STAGE_IN(kt)                                                                          \
  _Pragma("unroll")                                                                           \
  for (int i = 0; i < 2; ++i) {                                                              \
    int e = tid + i * 512;                                                                   \
    if (e < 768) {                                                                           \
      int ch = e / 48, rem = e % 48, r = rem >> 3, w4 = rem & 7;                             \
      int hh = h0 - 1 + r;                                                                   \
      float4 v = make_float4(0.f, 0.f, 0.f, 0.f);                                            \
      if (hh >= 0 && hh < 32)                                                                \
        v = *(const float4*)&inb[(size_t)((kt) * 16 + ch) * 1024 + hh * 32 + w4 * 4];        \
      *(float4*)&Is[(kt) & 1][ch][r][w4 * 4] = v;                                            \
    }                                                                                        \
  }

#define STAGE_B(kt)                                                                           \
  _Pragma("unroll")                                                                           \
  for (int l = 0; l < 8; ++l)                                                                \
    __builtin_amdgcn_global_load_lds(                                                        \
        (const AS1 void*)(sB + (size_t)l * 65536 + (kt) * 64),                               \
        (AS3 void*)&Bs[l * 4096 + bdst], 16, 0, 0);

  // prologue: input(0) staged and published
  STAGE_IN(0)
  LGKMCNT0; BARRIER;

  for (int kt = 0; kt < 16; ++kt) {
    // ---- Phase A (produce): input(kt+1) stage, B(kt) stage, conv(kt) -> As
    if (kt < 15) { STAGE_IN(kt + 1) }
    STAGE_B(kt)
    {
      int ib = kt & 1;
      #pragma unroll
      for (int b = 0; b < 2; ++b) {
        int ch = ch2 * 2 + b;
        float v[4], mL[4], mR[4];
        #pragma unroll
        for (int r = 0; r < 4; ++r) {
          float x = Is[ib][ch][hp * 2 + r][cw];
          v[r] = x;
          float up = __shfl_up(x, 1);
          float dn = __shfl_down(x, 1);
          mL[r] = (cw == 0) ? 0.f : up;
          mR[r] = (cw == 31) ? 0.f : dn;
        }
        #pragma unroll
        for (int j = 0; j < 2; ++j) {
          float s[4];
          #pragma unroll
          for (int p = 0; p < 4; ++p) {
            float a_ = 0.f;
            #pragma unroll
            for (int dr = 0; dr < 3; ++dr) {
              a_ += mL[j + dr] * sfr[p * 9 + dr * 3 + 0];
              a_ += v[j + dr]  * sfr[p * 9 + dr * 3 + 1];
              a_ += mR[j + dr] * sfr[p * 9 + dr * 3 + 2];
            }
            s[p] = a_;
          }
          unsigned lo = (unsigned)f2bf(s[0]) | ((unsigned)f2bf(s[1]) << 16);
          unsigned hi = (unsigned)f2bf(s[2]) | ((unsigned)f2bf(s[3]) << 16);
          int row = (hp * 2 + j) * 32 + cw;
          uint2 pk; pk.x = lo; pk.y = hi;
          *(uint2*)&As[row * 64 + (ch2 ^ (cw & 7)) * 8 + b * 4] = pk;
        }
      }
    }
    // certify: all ds ops done + own DMA (B) landed, BEFORE readers released
    LGKMCNT0; VMCNT0; BARRIER;

    // ---- Phase B (consume): 24 ds_read_b128 + 64 MFMA
    #pragma unroll
    for (int ks = 0; ks < 2; ++ks) {
      int kph = ks ? kph1 : kph0;
      bf16x8 af[4];
      #pragma unroll
      for (int mf = 0; mf < 4; ++mf)
        af[mf] = *(const bf16x8*)&As[(wm + mf * 16 + lr) * 64 + kph];
      #pragma unroll
      for (int ng = 0; ng < 2; ++ng) {
        bf16x8 bf4[4];
        #pragma unroll
        for (int nq = 0; nq < 4; ++nq)
          bf4[nq] = *(const bf16x8*)&Bs[(wn + ng * 64 + nq * 16 + lr) * 64 + kph];
        __builtin_amdgcn_s_setprio(1);
        #pragma unroll
        for (int mf = 0; mf < 4; ++mf)
          #pragma unroll
          for (int nq = 0; nq < 4; ++nq)
            acc[mf][ng * 4 + nq] =
                __builtin_amdgcn_mfma_f32_16x16x32_bf16(af[mf], bf4[nq], acc[mf][ng * 4 + nq], 0, 0, 0);
        __builtin_amdgcn_s_setprio(0);
      }
    }
    LGKMCNT0; BARRIER;   // A/B reads retired before next Phase A overwrites
  }
#undef STAGE_IN
#undef STAGE_B

  // epilogue: lane holds D[m=kg*4+r][o=lr] per 16x16 frag
  #pragma unroll
  for (int mf = 0; mf < 4; ++mf)
    #pragma unroll
    for (int nf = 0; nf < 8; ++nf) {
      int mloc = hq * 128 + wm + mf * 16 + kg * 4;
      int o = wn + nf * 16 + lr;
      f32x4 vv = acc[mf][nf];
      vv[0] += bv[nf]; vv[1] += bv[nf]; vv[2] += bv[nf]; vv[3] += bv[nf];
      *(f32x4*)&out[(size_t)n * 524288 + (size_t)o * 1024 + mloc] = vv;
    }
}

extern "C" void kernel_launch(void* const* d_in, const int* in_sizes, int n_in,
                              void* d_out, int out_size, void* d_ws, size_t ws_size,
                              hipStream_t stream) {
  (void)in_sizes; (void)n_in; (void)out_size; (void)ws_size;
  const float* in   = (const float*)d_in[0];
  const float* sf   = (const float*)d_in[1];
  const float* f0   = (const float*)d_in[2];
  const float* f1   = (const float*)d_in[3];
  const float* lf   = (const float*)d_in[4];
  const float* bias = (const float*)d_in[5];
  float* out = (float*)d_out;

  char* ws = (char*)d_ws;
  ushort_t* chainT = (ushort_t*)ws;                 // 1 MB
  float*    g      = (float*)(ws + 1048576);        // 128 KB

  hipLaunchKernelGGL(chain_g_kernel, dim3(128),  dim3(256), 0, stream, f1, lf, g);
  hipLaunchKernelGGL(chain_kernel,   dim3(2048), dim3(256), 0, stream, f0, g, chainT);
  hipLaunchKernelGGL(fused_kernel,   dim3(256),  dim3(512), 0, stream, in, sf, chainT, bias, out);
}

// Round 10
// 74.212 us; speedup vs baseline: 1.5772x; 1.0336x over previous
//
#include <hip/hip_runtime.h>

typedef unsigned short ushort_t;
typedef __attribute__((ext_vector_type(8))) short bf16x8;
typedef __attribute__((ext_vector_type(4))) float f32x4;

__device__ __forceinline__ unsigned short f2bf(float f) {
  union { float f; unsigned u; } x; x.f = f;
  unsigned r = x.u + 0x7FFFu + ((x.u >> 16) & 1u);   // round-to-nearest-even
  return (unsigned short)(r >> 16);
}

// ---------------- chain part 1: g[b][q][y][c][z] = sum_r f1[b,q,r,y]*lf[c,r,z]
__global__ void chain_g_kernel(const float* __restrict__ f1,
                               const float* __restrict__ lf,
                               float* __restrict__ g) {
  int idx = blockIdx.x * 256 + threadIdx.x;           // 32768 total
  int z = idx & 7, c = (idx >> 3) & 3, y = (idx >> 5) & 7,
      q = (idx >> 8) & 15, b = idx >> 12;
  float s = 0.f;
  #pragma unroll
  for (int r = 0; r < 16; ++r)
    s += f1[((b * 16 + q) * 16 + r) * 8 + y] * lf[(c * 16 + r) * 8 + z];
  g[idx] = s;
}

// ---------------- chain part 2: chainT[o][k] = sum_q f0[a,p,q,x]*g[b,q,y,c,z]
// o = (x*8+y)*8+z ; k = ((a*8+b)*4+c)*4+p
__global__ void chain_kernel(const float* __restrict__ f0,
                             const float* __restrict__ g,
                             ushort_t* __restrict__ chainT) {
  int idx = blockIdx.x * 256 + threadIdx.x;           // 524288 total = o*1024+k
  int k = idx & 1023, o = idx >> 10;
  int p = k & 3, c = (k >> 2) & 3, b = (k >> 4) & 7, a = k >> 7;
  int z = o & 7, y = (o >> 3) & 7, x = o >> 6;
  float s = 0.f;
  #pragma unroll
  for (int q = 0; q < 16; ++q)
    s += f0[((a * 4 + p) * 16 + q) * 8 + x] *
         g[(((b * 16 + q) * 8 + y) * 4 + c) * 8 + z];
  chainT[idx] = f2bf(s);
}

// ---------------- FUSED conv+GEMM, pipelined.
// block = 128 pixels (n, 4 h-rows, 32 w) x all 512 o. Grid 256 = 1 block/CU.
// Per K-step kt (16 cin x 4 p = 64 k):
//   phase1: MFMA(kt) from As[kt&1]+Bs  ||  conv(kt+1)->As[(kt+1)&1]  ||  Is-write(kt+2)
//   phase2: stage B(kt+1) (8 gload_lds), issue input(kt+3) regs, vmcnt(3), barrier
// Sync rules: producer-side vmcnt before the releasing barrier; stage only after
// last-read's phase closed; counted vmcnt(3) = 8 B-loads retired, input stays in flight.
#define AS1 __attribute__((address_space(1)))
#define AS3 __attribute__((address_space(3)))
#define BARRIER  __builtin_amdgcn_s_barrier()
#define LGKMCNT0 asm volatile("s_waitcnt lgkmcnt(0)" ::: "memory")
#define VMCNT3   asm volatile("s_waitcnt vmcnt(3)" ::: "memory")
#define VMCNT0   asm volatile("s_waitcnt vmcnt(0)" ::: "memory")

__global__ __launch_bounds__(512, 2) void fused_kernel(const float* __restrict__ in,
                                                       const float* __restrict__ sf,
                                                       const ushort_t* __restrict__ chainT,
                                                       const float* __restrict__ bias,
                                                       float* __restrict__ out) {
  __shared__ __align__(16) ushort_t Bs[32768];      // 64 KB  [512 rows][64 k] swizzled
  __shared__ __align__(16) ushort_t As[2][8192];    // 2x16 KB [128 rows][64 k] swizzled
  __shared__ __align__(16) float Is[6528];          // 2 x 16ch x 6r x 34 (cols 32,33 = zero halo)

  int tid = threadIdx.x;
  int bid = blockIdx.x;                             // 256 blocks
  int wg = (bid & 7) * 32 + (bid >> 3);             // XCD swizzle
  int n = wg >> 3, hq = wg & 7;
  int h0 = hq * 4;

  int lane = tid & 63, wv = tid >> 6;
  int wm = (wv >> 2) * 64, wn = (wv & 3) * 128;     // per-wave 64 x 128
  int lr = lane & 15, kg = lane >> 4;
  int kph0 = ((kg * 8) ^ ((lane & 7) * 8));
  int kph1 = ((32 + kg * 8) ^ ((lane & 7) * 8));

  // B staging (proven): source chunk pre-swizzled, LDS linear (tid*8 elems)
  int srow = tid >> 3;
  int scol = ((tid & 7) ^ (srow & 7)) * 8;
  const ushort_t* sB = chainT + (size_t)srow * 1024 + scol;

  // conv mapping: wave wv owns channel pair ch2=wv; lane = cw + 32*hp
  int cw = tid & 31, hp = (tid >> 5) & 1, ch2 = wv;
  int clm = (cw == 0) ? 33 : cw - 1;
  int crp = (cw == 31) ? 32 : cw + 1;
  int aswz = (ch2 ^ (cw & 7)) * 8;

  // input staging decode (3 uniform float2 per thread)
  int isrc[3], ild[3], izer[3];
  #pragma unroll
  for (int i = 0; i < 3; ++i) {
    int e = tid + i * 512;                          // 0..1535 = 16ch x 6r x 16 float2
    int ch = e / 96, rem = e % 96, r = rem >> 4, w2 = rem & 15;
    int hh = h0 - 1 + r;
    int hcl = hh < 0 ? 0 : (hh > 31 ? 31 : hh);
    izer[i] = (hh < 0) | (hh > 31);
    isrc[i] = ch * 1024 + hcl * 32 + w2 * 2;
    ild[i]  = ch * 204 + r * 34 + w2 * 2;
  }
  const float* inb = in + (size_t)n * 262144;
  float2 rin[3];

  float sfr[36];
  #pragma unroll
  for (int i = 0; i < 36; ++i)
    sfr[i] = __int_as_float(__builtin_amdgcn_readfirstlane(__float_as_int(sf[i])));

  float bv[8];
  #pragma unroll
  for (int nf = 0; nf < 8; ++nf) bv[nf] = bias[wn + nf * 16 + lr];

  f32x4 acc[4][8];
  #pragma unroll
  for (int i = 0; i < 4; ++i)
    #pragma unroll
    for (int j = 0; j < 8; ++j) acc[i][j] = (f32x4){0.f, 0.f, 0.f, 0.f};

#define ISSUE_IN(KT)                                                                     \
  _Pragma("unroll")                                                                      \
  for (int i = 0; i < 3; ++i)                                                            \
    rin[i] = *(const float2*)&inb[(size_t)(KT) * 16384 + isrc[i]];

#define WRITE_IN(IB)                                                                     \
  _Pragma("unroll")                                                                      \
  for (int i = 0; i < 3; ++i) {                                                          \
    float2 v = rin[i];                                                                   \
    if (izer[i]) { v.x = 0.f; v.y = 0.f; }                                               \
    *(float2*)&Is[(IB) * 3264 + ild[i]] = v;                                             \
  }

#define STAGE_B(KT)                                                                      \
  _Pragma("unroll")                                                                      \
  for (int l = 0; l < 8; ++l)                                                            \
    __builtin_amdgcn_global_load_lds(                                                    \
        (const AS1 void*)(sB + (size_t)l * 65536 + (KT) * 64),                           \
        (AS3 void*)&Bs[l * 4096 + tid * 8], 16, 0, 0);

#define CONV(IB, AB)                                                                     \
  {                                                                                      \
    float tap[2][4][3];                                                                  \
    _Pragma("unroll")                                                                    \
    for (int b = 0; b < 2; ++b) {                                                        \
      const float* isp = &Is[(IB) * 3264 + (ch2 * 2 + b) * 204];                         \
      _Pragma("unroll")                                                                  \
      for (int r4 = 0; r4 < 4; ++r4) {                                                   \
        int rb = (hp * 2 + r4) * 34;                                                     \
        tap[b][r4][0] = isp[rb + clm];                                                   \
        tap[b][r4][1] = isp[rb + cw];                                                    \
        tap[b][r4][2] = isp[rb + crp];                                                   \
      }                                                                                  \
    }                                                                                    \
    _Pragma("unroll")                                                                    \
    for (int j = 0; j < 2; ++j) {                                                        \
      unsigned pw[4];                                                                    \
      _Pragma("unroll")                                                                  \
      for (int b = 0; b < 2; ++b) {                                                      \
        float s[4];                                                                      \
        _Pragma("unroll")                                                                \
        for (int p = 0; p < 4; ++p) {                                                    \
          float a_ = 0.f;                                                                \
          _Pragma("unroll")                                                              \
          for (int dr = 0; dr < 3; ++dr)                                                 \
            _Pragma("unroll")                                                            \
            for (int dt = 0; dt < 3; ++dt)                                               \
              a_ += tap[b][j + dr][dt] * sfr[p * 9 + dr * 3 + dt];                       \
          s[p] = a_;                                                                     \
        }                                                                                \
        pw[b * 2 + 0] = (unsigned)f2bf(s[0]) | ((unsigned)f2bf(s[1]) << 16);             \
        pw[b * 2 + 1] = (unsigned)f2bf(s[2]) | ((unsigned)f2bf(s[3]) << 16);             \
      }                                                                                  \
      uint4 pk; pk.x = pw[0]; pk.y = pw[1]; pk.z = pw[2]; pk.w = pw[3];                  \
      int row = (hp * 2 + j) * 32 + cw;                                                  \
      *(uint4*)&As[AB][row * 64 + aswz] = pk;                                            \
    }                                                                                    \
  }

#define MFMA_PHASE(AB)                                                                   \
  _Pragma("unroll")                                                                      \
  for (int ks = 0; ks < 2; ++ks) {                                                       \
    int kph = ks ? kph1 : kph0;                                                          \
    bf16x8 af[4];                                                                        \
    _Pragma("unroll")                                                                    \
    for (int mf = 0; mf < 4; ++mf)                                                       \
      af[mf] = *(const bf16x8*)&As[AB][(wm + mf * 16 + lr) * 64 + kph];                  \
    _Pragma("unroll")                                                                    \
    for (int ng = 0; ng < 2; ++ng) {                                                     \
      bf16x8 bq[4];                                                                      \
      _Pragma("unroll")                                                                  \
      for (int nq = 0; nq < 4; ++nq)                                                     \
        bq[nq] = *(const bf16x8*)&Bs[(wn + ng * 64 + nq * 16 + lr) * 64 + kph];          \
      __builtin_amdgcn_s_setprio(1);                                                     \
      _Pragma("unroll")                                                                  \
      for (int mf = 0; mf < 4; ++mf)                                                     \
        _Pragma("unroll")                                                                \
        for (int nq = 0; nq < 4; ++nq)                                                   \
          acc[mf][ng * 4 + nq] = __builtin_amdgcn_mfma_f32_16x16x32_bf16(                \
              af[mf], bq[nq], acc[mf][ng * 4 + nq], 0, 0, 0);                            \
      __builtin_amdgcn_s_setprio(0);                                                     \
    }                                                                                    \
  }

  // ---- prologue
  if (tid < 384) {                                  // zero halo cols (both Is bufs)
    int bb = tid / 192, rem = tid % 192, ch = rem / 12, rr = rem % 12;
    Is[bb * 3264 + ch * 204 + (rr >> 1) * 34 + 32 + (rr & 1)] = 0.f;
  }
  ISSUE_IN(0)
  WRITE_IN(0)                                       // compiler waits in(0) regs
  ISSUE_IN(1)
  LGKMCNT0; BARRIER;                                // Is[0] + halos published
  CONV(0, 0)                                        // conv(0) -> As[0]
  WRITE_IN(1)                                       // Is[1] (drains in(1))
  STAGE_B(0)
  ISSUE_IN(2)
  LGKMCNT0; VMCNT3; BARRIER;                        // As[0], Is[1], Bs(0) published

  #pragma unroll 1
  for (int I = 0; I < 8; ++I) {
    // ---- kt = 2I (even): MFMA As[0] | conv(2I+1)->As[1] | Is-write in(2I+2)->buf0
    MFMA_PHASE(0)
    CONV(1, 1)
    if (I < 7) { WRITE_IN(0) }
    LGKMCNT0; BARRIER;
    STAGE_B(2 * I + 1)
    if (I < 7) { ISSUE_IN(2 * I + 3) VMCNT3; } else { VMCNT0; }
    BARRIER;
    // ---- kt = 2I+1 (odd)
    MFMA_PHASE(1)
    if (I < 7) { CONV(0, 0) WRITE_IN(1) }
    LGKMCNT0; BARRIER;
    if (I < 7) {
      STAGE_B(2 * I + 2)
      if (I < 6) { ISSUE_IN(2 * I + 4) VMCNT3; } else { VMCNT0; }
    }
    BARRIER;
  }

  // ---- epilogue: lane holds D[m=kg*4+r][o=lr] per 16x16 frag
  #pragma unroll
  for (int mf = 0; mf < 4; ++mf)
    #pragma unroll
    for (int nf = 0; nf < 8; ++nf) {
      int mloc = hq * 128 + wm + mf * 16 + kg * 4;
      int o = wn + nf * 16 + lr;
      f32x4 vv = acc[mf][nf];
      vv[0] += bv[nf]; vv[1] += bv[nf]; vv[2] += bv[nf]; vv[3] += bv[nf];
      *(f32x4*)&out[(size_t)n * 524288 + (size_t)o * 1024 + mloc] = vv;
    }
}

extern "C" void kernel_launch(void* const* d_in, const int* in_sizes, int n_in,
                              void* d_out, int out_size, void* d_ws, size_t ws_size,
                              hipStream_t stream) {
  (void)in_sizes; (void)n_in; (void)out_size; (void)ws_size;
  const float* in   = (const float*)d_in[0];
  const float* sf   = (const float*)d_in[1];
  const float* f0   = (const float*)d_in[2];
  const float* f1   = (const float*)d_in[3];
  const float* lf   = (const float*)d_in[4];
  const float* bias = (const float*)d_in[5];
  float* out = (float*)d_out;

  char* ws = (char*)d_ws;
  ushort_t* chainT = (ushort_t*)ws;                 // 1 MB
  float*    g      = (float*)(ws + 1048576);        // 128 KB

  hipLaunchKernelGGL(chain_g_kernel, dim3(128),  dim3(256), 0, stream, f1, lf, g);
  hipLaunchKernelGGL(chain_kernel,   dim3(2048), dim3(256), 0, stream, f0, g, chainT);
  hipLaunchKernelGGL(fused_kernel,   dim3(256),  dim3(512), 0, stream, in, sf, chainT, bias, out);
}